// Round 7
// baseline (51.046 us; speedup 1.0000x reference)
//
#include <hip/hip_runtime.h>

typedef float v2f __attribute__((ext_vector_type(2)));

#define BATCH  8
#define NPTS   4096
#define NSLICE 64                 // target-set split per (dir,b)
#define SLICE  (NPTS / NSLICE)    // 64 targets per block
#define TPB1   256                // 4 waves/block, 4 blocks/CU -> 4 waves/SIMD
#define QPT    16                 // queries per thread (4096 / 256)

// Stage 1: grid = 2 dirs x 8 batches x 64 target-slices = 1024 blocks.
// Queries are packed PAIRWISE into float2 ext-vectors so the inner step is
// v_pk_fma_f32 (2 distance-evals per instr): per target per query-pair =
// 3 pk_fma + 2 v_min = 2.5 VALU instr/pair (vs 4 scalar). Targets broadcast
// from LDS (-2y0,-2y1,-2y2,||y||^2); splat into both halves (op_sel).
// Partial per-query mins stored with plain coalesced stores (no atomics —
// device-scope RMWs were the round-4 disaster).
__global__ __launch_bounds__(TPB1, 4) void chamfer_stage1(
    const float* __restrict__ preds,
    const float* __restrict__ gts,
    float* __restrict__ part)     // [16 db][NSLICE][NPTS]
{
    const int blk   = blockIdx.x;
    const int slice = blk % NSLICE;
    const int db    = blk / NSLICE;    // dir*8 + b
    const int dir   = db >> 3;
    const int b     = db & 7;

    const float* Q = dir ? gts   : preds;   // query set
    const float* T = dir ? preds : gts;     // target set

    __shared__ float4 sT[SLICE];            // 1 KiB

    const float* Tb = T + ((size_t)b * NPTS + slice * SLICE) * 3;
    if (threadIdx.x < SLICE) {
        const int j = threadIdx.x;
        const float y0 = Tb[j * 3 + 0];
        const float y1 = Tb[j * 3 + 1];
        const float y2 = Tb[j * 3 + 2];
        sT[j] = make_float4(-2.0f * y0, -2.0f * y1, -2.0f * y2,
                            y0 * y0 + y1 * y1 + y2 * y2);
    }

    // This thread's 16 consecutive queries (48 floats = 12 float4),
    // repacked as 8 query-PAIRS: qx_p = {x(2p), x(2p+1)}, etc.
    const int q0 = threadIdx.x * QPT;
    const float4* p4 = reinterpret_cast<const float4*>(
        Q + ((size_t)b * NPTS + q0) * 3);
    const float4 v0  = p4[0],  v1  = p4[1],  v2  = p4[2];
    const float4 v3  = p4[3],  v4  = p4[4],  v5  = p4[5];
    const float4 v6  = p4[6],  v7  = p4[7],  v8  = p4[8];
    const float4 v9  = p4[9],  v10 = p4[10], v11 = p4[11];

    // flat index i (0..47) = query (i/3) component (i%3); F(i) = v{i/4}.{i%4}
    const v2f qx0 = {v0.x,  v0.w};  const v2f qy0 = {v0.y,  v1.x};  const v2f qz0 = {v0.z,  v1.y};
    const v2f qx1 = {v1.z,  v2.y};  const v2f qy1 = {v1.w,  v2.z};  const v2f qz1 = {v2.x,  v2.w};
    const v2f qx2 = {v3.x,  v3.w};  const v2f qy2 = {v3.y,  v4.x};  const v2f qz2 = {v3.z,  v4.y};
    const v2f qx3 = {v4.z,  v5.y};  const v2f qy3 = {v4.w,  v5.z};  const v2f qz3 = {v5.x,  v5.w};
    const v2f qx4 = {v6.x,  v6.w};  const v2f qy4 = {v6.y,  v7.x};  const v2f qz4 = {v6.z,  v7.y};
    const v2f qx5 = {v7.z,  v8.y};  const v2f qy5 = {v7.w,  v8.z};  const v2f qz5 = {v8.x,  v8.w};
    const v2f qx6 = {v9.x,  v9.w};  const v2f qy6 = {v9.y,  v10.x}; const v2f qz6 = {v9.z,  v10.y};
    const v2f qx7 = {v10.z, v11.y}; const v2f qy7 = {v10.w, v11.z}; const v2f qz7 = {v11.x, v11.w};

    __syncthreads();

    v2f m0 = {3.4e38f, 3.4e38f}, m1 = m0, m2 = m0, m3 = m0;
    v2f m4 = m0, m5 = m0, m6 = m0, m7 = m0;

    // e = ||y||^2 - 2*dot(q,y)  (= ||q-y||^2 - ||q||^2; rx added in stage 2)
    #define DO_P(p) { \
        const v2f e = __builtin_elementwise_fma(qx##p, yx, \
                       __builtin_elementwise_fma(qy##p, yy, \
                        __builtin_elementwise_fma(qz##p, yz, yw))); \
        m##p = __builtin_elementwise_min(m##p, e); }

    #pragma unroll 4
    for (int j = 0; j < SLICE; ++j) {
        const float4 y = sT[j];
        const v2f yx = {y.x, y.x};
        const v2f yy = {y.y, y.y};
        const v2f yz = {y.z, y.z};
        const v2f yw = {y.w, y.w};
        DO_P(0) DO_P(1) DO_P(2) DO_P(3)
        DO_P(4) DO_P(5) DO_P(6) DO_P(7)
    }
    #undef DO_P

    // Coalesced 64 B/thread store: part[db][slice][q0..q0+15]
    // (pair p holds queries 2p, 2p+1 -> already in ascending order)
    float4* b4 = reinterpret_cast<float4*>(
        part + ((size_t)db * NSLICE + slice) * NPTS + q0);
    b4[0] = make_float4(m0.x, m0.y, m1.x, m1.y);
    b4[1] = make_float4(m2.x, m2.y, m3.x, m3.y);
    b4[2] = make_float4(m4.x, m4.y, m5.x, m5.y);
    b4[3] = make_float4(m6.x, m6.y, m7.x, m7.y);
}

// Stage 2: one thread per query; min over the 64 slice-partials
// (lane-coalesced strided loads), add rx, block-reduce, one atomicAdd.
#define TPB2 256
__global__ __launch_bounds__(TPB2) void chamfer_stage2(
    const float* __restrict__ preds,
    const float* __restrict__ gts,
    const float* __restrict__ part,
    float* __restrict__ out)
{
    const int g   = blockIdx.x * TPB2 + threadIdx.x;   // [0, 2*8*4096)
    const int db  = g >> 12;
    const int q   = g & (NPTS - 1);
    const int dir = db >> 3;
    const int b   = db & 7;

    const float* pp = part + (size_t)db * NSLICE * NPTS + q;
    float m = 3.4e38f;
    #pragma unroll 8
    for (int s = 0; s < NSLICE; ++s)
        m = fminf(m, pp[(size_t)s * NPTS]);

    const float* Q = dir ? gts : preds;
    const size_t qi = ((size_t)b * NPTS + q) * 3;
    const float x0 = Q[qi + 0];
    const float x1 = Q[qi + 1];
    const float x2 = Q[qi + 2];
    float s = m + (x0 * x0 + x1 * x1 + x2 * x2);

    #pragma unroll
    for (int off = 32; off > 0; off >>= 1)
        s += __shfl_down(s, off, 64);

    __shared__ float red[TPB2 / 64];
    const int lane = threadIdx.x & 63;
    const int wid  = threadIdx.x >> 6;
    if (lane == 0) red[wid] = s;
    __syncthreads();
    if (threadIdx.x == 0) {
        float t = 0.0f;
        #pragma unroll
        for (int w = 0; w < TPB2 / 64; ++w) t += red[w];
        atomicAdd(out, t);
    }
}

extern "C" void kernel_launch(void* const* d_in, const int* in_sizes, int n_in,
                              void* d_out, int out_size, void* d_ws, size_t ws_size,
                              hipStream_t stream) {
    const float* preds = (const float*)d_in[0];
    const float* gts   = (const float*)d_in[1];
    float* out  = (float*)d_out;
    float* part = (float*)d_ws;   // 16 db x 64 slices x 4096 floats = 16 MiB

    // part is fully written by stage 1 before stage 2 reads it — no init.
    hipMemsetAsync(out, 0, sizeof(float), stream);

    chamfer_stage1<<<dim3(2 * BATCH * NSLICE), TPB1, 0, stream>>>(preds, gts, part);
    chamfer_stage2<<<dim3(2 * BATCH * NPTS / TPB2), TPB2, 0, stream>>>(preds, gts, part, out);
}

// Round 8
// 32.350 us; speedup vs baseline: 1.5779x; 1.5779x over previous
//
#include <hip/hip_runtime.h>

#define BATCH  8
#define NPTS   4096
#define NSLICE 16                 // target-set split per (dir,b)
#define SLICE  (NPTS / NSLICE)    // 256 targets per block
#define TPB1   512                // 8 waves/block, 1 block/CU
#define QPT    8                  // queries per thread (4096 / 512)

// Stage 1: grid = 2 dirs x 8 batches x 16 target-slices = 256 blocks.
// Round-5 proven skeleton (36.2 us): registers hold 8 queries/thread as
// NAMED scalars, block stages 256 targets in LDS as (-2y,||y||^2), partial
// mins stored with plain coalesced stores (no device atomics!).
// Round-8 deltas: (a) process 2 targets/iter and reduce with
// fminf(m,fminf(ea,eb)) -> v_min3_f32 (7 instr per 2 pairs, was 8);
// (b) block 0 zeroes `out` here, dropping the separate memset dispatch
// (kernel-end release makes it visible to stage2, same as `part`).
__global__ __launch_bounds__(TPB1, 2) void chamfer_stage1(
    const float* __restrict__ preds,
    const float* __restrict__ gts,
    float* __restrict__ part,     // [16 db][NSLICE][NPTS]
    float* __restrict__ out)
{
    const int blk   = blockIdx.x;
    const int slice = blk % NSLICE;
    const int db    = blk / NSLICE;    // dir*8 + b
    const int dir   = db >> 3;
    const int b     = db & 7;

    if (blk == 0 && threadIdx.x == 0) out[0] = 0.0f;

    const float* Q = dir ? gts   : preds;   // query set
    const float* T = dir ? preds : gts;     // target set

    __shared__ float4 sT[SLICE];            // 4 KiB

    const float* Tb = T + ((size_t)b * NPTS + slice * SLICE) * 3;
    if (threadIdx.x < SLICE) {
        const int j = threadIdx.x;
        const float y0 = Tb[j * 3 + 0];
        const float y1 = Tb[j * 3 + 1];
        const float y2 = Tb[j * 3 + 2];
        sT[j] = make_float4(-2.0f * y0, -2.0f * y1, -2.0f * y2,
                            y0 * y0 + y1 * y1 + y2 * y2);
    }

    // This thread's 8 consecutive queries (24 floats = 6 float4).
    const int q0 = threadIdx.x * QPT;
    const float4* p4 = reinterpret_cast<const float4*>(
        Q + ((size_t)b * NPTS + q0) * 3);
    const float4 v0 = p4[0], v1 = p4[1], v2 = p4[2];
    const float4 v3 = p4[3], v4 = p4[4], v5 = p4[5];

    const float qx0 = v0.x, qy0 = v0.y, qz0 = v0.z;
    const float qx1 = v0.w, qy1 = v1.x, qz1 = v1.y;
    const float qx2 = v1.z, qy2 = v1.w, qz2 = v2.x;
    const float qx3 = v2.y, qy3 = v2.z, qz3 = v2.w;
    const float qx4 = v3.x, qy4 = v3.y, qz4 = v3.z;
    const float qx5 = v3.w, qy5 = v4.x, qz5 = v4.y;
    const float qx6 = v4.z, qy6 = v4.w, qz6 = v5.x;
    const float qx7 = v5.y, qy7 = v5.z, qz7 = v5.w;

    __syncthreads();

    float m0 = 3.4e38f, m1 = 3.4e38f, m2 = 3.4e38f, m3 = 3.4e38f;
    float m4 = 3.4e38f, m5 = 3.4e38f, m6 = 3.4e38f, m7 = 3.4e38f;

    // e = ||y||^2 - 2*dot(q,y)  (= ||q-y||^2 - ||q||^2; rx added in stage 2)
    // Two targets per iter; fminf(m, fminf(ea,eb)) fuses to v_min3_f32.
    #define DO_Q2(k) { \
        const float ea = fmaf(qx##k, ya.x, fmaf(qy##k, ya.y, \
                              fmaf(qz##k, ya.z, ya.w))); \
        const float eb = fmaf(qx##k, yb.x, fmaf(qy##k, yb.y, \
                              fmaf(qz##k, yb.z, yb.w))); \
        m##k = fminf(m##k, fminf(ea, eb)); }

    #pragma unroll 4
    for (int j = 0; j < SLICE; j += 2) {
        const float4 ya = sT[j];
        const float4 yb = sT[j + 1];
        DO_Q2(0) DO_Q2(1) DO_Q2(2) DO_Q2(3)
        DO_Q2(4) DO_Q2(5) DO_Q2(6) DO_Q2(7)
    }
    #undef DO_Q2

    // Coalesced 32 B/thread store: part[db][slice][q0..q0+7]
    float4* b4 = reinterpret_cast<float4*>(
        part + ((size_t)db * NSLICE + slice) * NPTS + q0);
    b4[0] = make_float4(m0, m1, m2, m3);
    b4[1] = make_float4(m4, m5, m6, m7);
}

// Stage 2: one thread per query; min over the 16 slice-partials
// (lane-coalesced strided loads), add rx, block-reduce, one atomicAdd.
#define TPB2 256
__global__ __launch_bounds__(TPB2) void chamfer_stage2(
    const float* __restrict__ preds,
    const float* __restrict__ gts,
    const float* __restrict__ part,
    float* __restrict__ out)
{
    const int g   = blockIdx.x * TPB2 + threadIdx.x;   // [0, 2*8*4096)
    const int db  = g >> 12;
    const int q   = g & (NPTS - 1);
    const int dir = db >> 3;
    const int b   = db & 7;

    const float* pp = part + (size_t)db * NSLICE * NPTS + q;
    float m = 3.4e38f;
    #pragma unroll
    for (int s = 0; s < NSLICE; ++s)
        m = fminf(m, pp[(size_t)s * NPTS]);

    const float* Q = dir ? gts : preds;
    const size_t qi = ((size_t)b * NPTS + q) * 3;
    const float x0 = Q[qi + 0];
    const float x1 = Q[qi + 1];
    const float x2 = Q[qi + 2];
    float s = m + (x0 * x0 + x1 * x1 + x2 * x2);

    #pragma unroll
    for (int off = 32; off > 0; off >>= 1)
        s += __shfl_down(s, off, 64);

    __shared__ float red[TPB2 / 64];
    const int lane = threadIdx.x & 63;
    const int wid  = threadIdx.x >> 6;
    if (lane == 0) red[wid] = s;
    __syncthreads();
    if (threadIdx.x == 0) {
        float t = 0.0f;
        #pragma unroll
        for (int w = 0; w < TPB2 / 64; ++w) t += red[w];
        atomicAdd(out, t);
    }
}

extern "C" void kernel_launch(void* const* d_in, const int* in_sizes, int n_in,
                              void* d_out, int out_size, void* d_ws, size_t ws_size,
                              hipStream_t stream) {
    const float* preds = (const float*)d_in[0];
    const float* gts   = (const float*)d_in[1];
    float* out  = (float*)d_out;
    float* part = (float*)d_ws;   // 16 db x 16 slices x 4096 floats = 4 MiB

    // Only 2 dispatches: stage1 zeroes `out` itself; `part` is fully
    // written by stage 1 before stage 2 reads it — no memsets needed.
    chamfer_stage1<<<dim3(2 * BATCH * NSLICE), TPB1, 0, stream>>>(preds, gts, part, out);
    chamfer_stage2<<<dim3(2 * BATCH * NPTS / TPB2), TPB2, 0, stream>>>(preds, gts, part, out);
}